// Round 1
// baseline (52.496 us; speedup 1.0000x reference)
//
#include <hip/hip_runtime.h>
#include <math.h>

#define BATCH 16
#define NTGT 32
#define NUM_CLASSES 80
#define REG_MAX 16
#define NBOX (4 * REG_MAX)   // 64
#define NCH 144              // 64 box + 80 cls
#define NITEMS (3 * BATCH * NTGT)  // 1536 work items

__global__ void yolo_loss_main(const float* __restrict__ p0,
                               const float* __restrict__ p1,
                               const float* __restrict__ p2,
                               const float* __restrict__ targets,
                               float* __restrict__ ws) {
    int wave = (blockIdx.x * blockDim.x + threadIdx.x) >> 6;
    int lane = threadIdx.x & 63;
    if (wave >= NITEMS) return;

    int s = wave / (BATCH * NTGT);
    int rem = wave - s * (BATCH * NTGT);
    int b = rem / NTGT;
    int n = rem - b * NTGT;

    const float* pred;
    int hdim, wdim, stride;
    if (s == 0)      { pred = p0; hdim = 80; wdim = 80; stride = 8;  }
    else if (s == 1) { pred = p1; hdim = 40; wdim = 40; stride = 16; }
    else             { pred = p2; hdim = 20; wdim = 20; stride = 32; }

    const float* t = targets + (size_t)(b * NTGT + n) * 5;
    float x1 = t[0], y1 = t[1], x2 = t[2], y2 = t[3];
    int tcls = (int)t[4];
    float inv_s = 1.0f / (float)stride;
    float cx = (x1 + x2) * 0.5f * inv_s;   // cg[...,0] -> gj
    float cy = (y1 + y2) * 0.5f * inv_s;   // cg[...,1] -> gi
    // clip on float, then truncate-cast (matches jnp.clip(...).astype(int32))
    float cyc = fminf(fmaxf(cy, 0.0f), (float)(hdim - 1));
    float cxc = fminf(fmaxf(cx, 0.0f), (float)(wdim - 1));
    int gi = (int)cyc;
    int gj = (int)cxc;

    size_t hw = (size_t)hdim * wdim;
    const float* base = pred + (size_t)b * NCH * hw + (size_t)gi * wdim + gj;

    float box_sum = 0.0f, cls_sum = 0.0f;
    #pragma unroll
    for (int c0 = 0; c0 < NCH; c0 += 64) {
        int c = c0 + lane;
        if (c < NCH) {
            float x = base[(size_t)c * hw];
            if (c < NBOX) {
                box_sum += x;
            } else {
                int k = c - NBOX;
                float lab = (k == tcls) ? 1.0f : 0.0f;
                cls_sum += fmaxf(x, 0.0f) - x * lab + log1pf(expf(-fabsf(x)));
            }
        }
    }

    // 64-lane butterfly reduction
    #pragma unroll
    for (int off = 32; off; off >>= 1) {
        box_sum += __shfl_xor(box_sum, off);
        cls_sum += __shfl_xor(cls_sum, off);
    }
    if (lane == 0) {
        // per-item contributions: box = -(mean over 64)*0.1 ; cls = sum/80
        atomicAdd(&ws[0], -box_sum * (0.1f / (float)NBOX));
        atomicAdd(&ws[1], cls_sum * (1.0f / (float)NUM_CLASSES));
    }
}

__global__ void yolo_loss_final(const float* __restrict__ ws,
                                float* __restrict__ out) {
    float inv_nt = 1.0f / (float)(BATCH * NTGT);
    float box = ws[0] * inv_nt;
    float cls = ws[1] * inv_nt;
    out[0] = 7.5f * box + 0.5f * cls;  // total (dfl term is 0)
    out[1] = box;
    out[2] = cls;
    out[3] = 0.0f;
}

extern "C" void kernel_launch(void* const* d_in, const int* in_sizes, int n_in,
                              void* d_out, int out_size, void* d_ws, size_t ws_size,
                              hipStream_t stream) {
    const float* p0 = (const float*)d_in[0];
    const float* p1 = (const float*)d_in[1];
    const float* p2 = (const float*)d_in[2];
    const float* targets = (const float*)d_in[3];
    float* ws = (float*)d_ws;
    float* out = (float*)d_out;

    hipMemsetAsync(ws, 0, 2 * sizeof(float), stream);

    // one 64-lane wave per (scale, b, n): 1536 waves -> 384 blocks of 256
    dim3 block(256);
    dim3 grid(NITEMS / 4);
    yolo_loss_main<<<grid, block, 0, stream>>>(p0, p1, p2, targets, ws);
    yolo_loss_final<<<1, 1, 0, stream>>>(ws, out);
}

// Round 2
// 14.664 us; speedup vs baseline: 3.5799x; 3.5799x over previous
//
#include <hip/hip_runtime.h>
#include <math.h>

#define BATCH 16
#define NTGT 32
#define NUM_CLASSES 80
#define REG_MAX 16
#define NBOX (4 * REG_MAX)   // 64
#define NCH 144              // 64 box + 80 cls
#define NITEMS (3 * BATCH * NTGT)  // 1536 work items

__global__ void yolo_loss_main(const float* __restrict__ p0,
                               const float* __restrict__ p1,
                               const float* __restrict__ p2,
                               const float* __restrict__ targets,
                               float* __restrict__ ws) {
    int wave = (blockIdx.x * blockDim.x + threadIdx.x) >> 6;
    int lane = threadIdx.x & 63;
    if (wave >= NITEMS) return;

    int s = wave / (BATCH * NTGT);
    int rem = wave - s * (BATCH * NTGT);
    int b = rem / NTGT;
    int n = rem - b * NTGT;

    const float* pred;
    int hdim, wdim, stride;
    if (s == 0)      { pred = p0; hdim = 80; wdim = 80; stride = 8;  }
    else if (s == 1) { pred = p1; hdim = 40; wdim = 40; stride = 16; }
    else             { pred = p2; hdim = 20; wdim = 20; stride = 32; }

    const float* t = targets + (size_t)(b * NTGT + n) * 5;
    float x1 = t[0], y1 = t[1], x2 = t[2], y2 = t[3];
    int tcls = (int)t[4];
    float inv_s = 1.0f / (float)stride;
    float cx = (x1 + x2) * 0.5f * inv_s;   // cg[...,0] -> gj
    float cy = (y1 + y2) * 0.5f * inv_s;   // cg[...,1] -> gi
    float cyc = fminf(fmaxf(cy, 0.0f), (float)(hdim - 1));
    float cxc = fminf(fmaxf(cx, 0.0f), (float)(wdim - 1));
    int gi = (int)cyc;
    int gj = (int)cxc;

    size_t hw = (size_t)hdim * wdim;
    const float* base = pred + (size_t)b * NCH * hw + (size_t)gi * wdim + gj;

    float box_sum = 0.0f, cls_sum = 0.0f;
    #pragma unroll
    for (int c0 = 0; c0 < NCH; c0 += 64) {
        int c = c0 + lane;
        if (c < NCH) {
            float x = base[(size_t)c * hw];
            if (c < NBOX) {
                box_sum += x;
            } else {
                int k = c - NBOX;
                float lab = (k == tcls) ? 1.0f : 0.0f;
                cls_sum += fmaxf(x, 0.0f) - x * lab + log1pf(expf(-fabsf(x)));
            }
        }
    }

    // 64-lane butterfly reduction
    #pragma unroll
    for (int off = 32; off; off >>= 1) {
        box_sum += __shfl_xor(box_sum, off);
        cls_sum += __shfl_xor(cls_sum, off);
    }
    if (lane == 0) {
        // per-wave partials; every slot written every call -> deterministic
        float2* w2 = (float2*)ws;
        float2 v;
        v.x = -box_sum * (0.1f / (float)NBOX);
        v.y = cls_sum * (1.0f / (float)NUM_CLASSES);
        w2[wave] = v;
    }
}

__global__ void yolo_reduce(const float* __restrict__ ws,
                            float* __restrict__ out) {
    __shared__ float sb[4], sc[4];
    int t = threadIdx.x;
    const float2* w2 = (const float2*)ws;
    float box = 0.0f, cls = 0.0f;
    #pragma unroll
    for (int k = 0; k < NITEMS / 256; ++k) {
        float2 v = w2[t + 256 * k];
        box += v.x;
        cls += v.y;
    }
    #pragma unroll
    for (int off = 32; off; off >>= 1) {
        box += __shfl_xor(box, off);
        cls += __shfl_xor(cls, off);
    }
    int wid = t >> 6;
    if ((t & 63) == 0) { sb[wid] = box; sc[wid] = cls; }
    __syncthreads();
    if (t == 0) {
        float b = sb[0] + sb[1] + sb[2] + sb[3];
        float c = sc[0] + sc[1] + sc[2] + sc[3];
        float inv_nt = 1.0f / (float)(BATCH * NTGT);
        b *= inv_nt;
        c *= inv_nt;
        out[0] = 7.5f * b + 0.5f * c;  // total (dfl term is 0)
        out[1] = b;
        out[2] = c;
        out[3] = 0.0f;
    }
}

extern "C" void kernel_launch(void* const* d_in, const int* in_sizes, int n_in,
                              void* d_out, int out_size, void* d_ws, size_t ws_size,
                              hipStream_t stream) {
    const float* p0 = (const float*)d_in[0];
    const float* p1 = (const float*)d_in[1];
    const float* p2 = (const float*)d_in[2];
    const float* targets = (const float*)d_in[3];
    float* ws = (float*)d_ws;
    float* out = (float*)d_out;

    dim3 block(256);
    dim3 grid(NITEMS / 4);  // one 64-lane wave per (scale, b, n)
    yolo_loss_main<<<grid, block, 0, stream>>>(p0, p1, p2, targets, ws);
    yolo_reduce<<<1, 256, 0, stream>>>(ws, out);
}